// Round 4
// baseline (11556.145 us; speedup 1.0000x reference)
//
#include <hip/hip_runtime.h>

// DIAGNOSTIC ROUND: pure fp32, no MFMA, no bf16 anywhere. Reference-faithful.
// Purpose: bisect the persistent ~0.1 absmax error (r1-r3) between
// "bf16/MFMA machinery bug" and "algebraic restructure mismatch".
// Algebra (same as r1-r3): ctx[h,d,e]=sum_n exp(k)v; denom[h,d]=sum_n exp(k);
// Cb[hd,c]=scale*sum_e (ctx/denom)*w_out[he,c]; z=qsm@Cb+b_out; LN.

#define SCALE 0.17677669529663687f

__global__ void kinit_f32(const float* __restrict__ w_qkv, float* __restrict__ WT,
                          float* __restrict__ zero_region, int nzero) {
  int i = blockIdx.x * blockDim.x + threadIdx.x;
  int stride = gridDim.x * blockDim.x;
  for (int j = i; j < nzero; j += stride) zero_region[j] = 0.0f;
  for (int j = i; j < 384 * 128; j += stride) {
    int f = j >> 7, c = j & 127;
    WT[j] = w_qkv[c * 384 + f];   // WT[f][c] fp32
  }
}

// ---- k1kv: per 64-row tile: k,v = x@Wkv (fp32 vector); Ek=exp(k), Vs=v in LDS;
//      serial fp32 outer product -> ctx/denom atomics.
__global__ __launch_bounds__(256, 1) void k1kv_f32(const float* __restrict__ xg,
                                                   const float* __restrict__ WT,
                                                   float* __restrict__ ctx,
                                                   float* __restrict__ denom) {
  __shared__ __align__(16) float xs[64 * 132];   // float4-aligned stride
  __shared__ float Ek[64 * 129];
  __shared__ float Vs[64 * 129];
  const int tid = threadIdx.x;
  const int row0 = blockIdx.x * 64;
  const int b = row0 >> 14;
  float4* xs4 = (float4*)xs;
  const float4* xg4 = (const float4*)xg;
  const float4* WT4 = (const float4*)WT;
  for (int i = tid; i < 2048; i += 256) {
    int row = i >> 5, c4 = i & 31;
    xs4[row * 33 + c4] = xg4[(row0 + row) * 32 + c4];
  }
  __syncthreads();
  const int r = tid & 63, fgrp = tid >> 6;
  float4 xr4[32];
  #pragma unroll 32
  for (int c4 = 0; c4 < 32; ++c4) xr4[c4] = xs4[r * 33 + c4];
  for (int p = 0; p < 8; ++p) {
    float acc[8];
    #pragma unroll
    for (int u = 0; u < 8; ++u) acc[u] = 0.f;
    const int fb = 128 + fgrp * 64 + p * 8;     // WT row base (k/v region)
    #pragma unroll 32
    for (int c4 = 0; c4 < 32; ++c4) {
      float4 xv = xr4[c4];
      #pragma unroll
      for (int u = 0; u < 8; ++u) {
        float4 wv = WT4[(fb + u) * 32 + c4];
        acc[u] += xv.x * wv.x + xv.y * wv.y + xv.z * wv.z + xv.w * wv.w;
      }
    }
    #pragma unroll
    for (int u = 0; u < 8; ++u) {
      int f = fgrp * 64 + p * 8 + u;            // 0..127 -> k, 128..255 -> v
      if (f < 128) Ek[r * 129 + f] = expf(acc[u]);
      else         Vs[r * 129 + (f - 128)] = acc[u];
    }
  }
  __syncthreads();
  const int h = tid >> 6, rem = tid & 63, d = rem >> 1, eh = rem & 1;
  const int kcol = h * 32 + d, vc = h * 32 + eh * 16;
  float cacc[16];
  #pragma unroll
  for (int j = 0; j < 16; ++j) cacc[j] = 0.f;
  float dsum = 0.f;
  for (int rr = 0; rr < 64; ++rr) {
    float ekv = Ek[rr * 129 + kcol];
    dsum += ekv;
    #pragma unroll
    for (int j = 0; j < 16; ++j) cacc[j] += ekv * Vs[rr * 129 + vc + j];
  }
  float* cdst = ctx + ((b * 4 + h) * 32 + d) * 32 + eh * 16;
  #pragma unroll
  for (int j = 0; j < 16; ++j) atomicAdd(cdst + j, cacc[j]);
  if (eh == 0) atomicAdd(denom + b * 128 + kcol, dsum);
}

// ---- k2: Cb[b][hd][c] = SCALE * sum_e (ctx[h,d,e]/denom[h,d]) * w_out[h*32+e][c], fp32
__global__ __launch_bounds__(256) void k2_f32(const float* __restrict__ ctx,
                                              const float* __restrict__ denom,
                                              const float* __restrict__ w_out,
                                              float* __restrict__ Cb) {
  __shared__ float c2[128][33];
  const int b = blockIdx.x, tid = threadIdx.x;
  for (int i = tid; i < 4096; i += 256) {
    int hd = i >> 5, e = i & 31;
    c2[hd][e] = SCALE * ctx[b * 4096 + i] / denom[b * 128 + hd];
  }
  __syncthreads();
  for (int o = tid; o < 16384; o += 256) {
    int hd = o >> 7, cc = o & 127, h = hd >> 5;
    float sacc = 0.f;
    #pragma unroll
    for (int e = 0; e < 32; ++e)
      sacc += c2[hd][e] * w_out[(h * 32 + e) * 128 + cc];
    Cb[b * 16384 + hd * 128 + cc] = sacc;
  }
}

// ---- k3: q = x@Wq (fp32); exact softmax over d; Z = qsm@Cb + b_out; LN; fp32 out
__global__ __launch_bounds__(256, 2) void k3_f32(const float* __restrict__ xg,
                                                 const float* __restrict__ WT,
                                                 const float* __restrict__ Cb,
                                                 const float* __restrict__ b_out,
                                                 const float* __restrict__ g_ln,
                                                 const float* __restrict__ b_ln,
                                                 float* __restrict__ outg) {
  __shared__ __align__(16) float xs[64 * 132];
  __shared__ float Qs[64 * 129];   // later overlaid as Zs
  const int tid = threadIdx.x;
  const int row0 = blockIdx.x * 64;
  const int b = row0 >> 14;
  float4* xs4 = (float4*)xs;
  const float4* xg4 = (const float4*)xg;
  const float4* WT4 = (const float4*)WT;
  const float4* Cb4 = (const float4*)(Cb + b * 16384);
  for (int i = tid; i < 2048; i += 256) {
    int row = i >> 5, c4 = i & 31;
    xs4[row * 33 + c4] = xg4[(row0 + row) * 32 + c4];
  }
  __syncthreads();
  const int r = tid & 63, fgrp = tid >> 6;
  {
    float4 xr4[32];
    #pragma unroll 32
    for (int c4 = 0; c4 < 32; ++c4) xr4[c4] = xs4[r * 33 + c4];
    for (int p = 0; p < 4; ++p) {
      float acc[8];
      #pragma unroll
      for (int u = 0; u < 8; ++u) acc[u] = 0.f;
      const int fb = fgrp * 32 + p * 8;         // q cols 0..127
      #pragma unroll 32
      for (int c4 = 0; c4 < 32; ++c4) {
        float4 xv = xr4[c4];
        #pragma unroll
        for (int u = 0; u < 8; ++u) {
          float4 wv = WT4[(fb + u) * 32 + c4];
          acc[u] += xv.x * wv.x + xv.y * wv.y + xv.z * wv.z + xv.w * wv.w;
        }
      }
      #pragma unroll
      for (int u = 0; u < 8; ++u) Qs[r * 129 + fb + u] = acc[u];
    }
  }
  __syncthreads();
  {   // exact softmax over d per (row, head): thread owns one (row, head)
    const int row = tid >> 2, hh = tid & 3;
    const int base = row * 129 + hh * 32;
    float e[32], m = -1e30f;
    #pragma unroll
    for (int j = 0; j < 32; ++j) { e[j] = Qs[base + j]; m = fmaxf(m, e[j]); }
    float s = 0.f;
    #pragma unroll
    for (int j = 0; j < 32; ++j) { e[j] = expf(e[j] - m); s += e[j]; }
    float inv = 1.0f / s;
    #pragma unroll
    for (int j = 0; j < 32; ++j) Qs[base + j] = e[j] * inv;   // no scale (in Cb)
  }
  __syncthreads();
  float qr[128];
  #pragma unroll 128
  for (int j = 0; j < 128; ++j) qr[j] = Qs[r * 129 + j];
  __syncthreads();   // all Qs reads done before Zs overlay
  float* Zs = Qs;
  for (int p = 0; p < 4; ++p) {
    const int c0 = fgrp * 32 + p * 8;
    float4 s0 = {0.f, 0.f, 0.f, 0.f}, s1 = {0.f, 0.f, 0.f, 0.f};
    #pragma unroll 128
    for (int hd = 0; hd < 128; ++hd) {
      float qv = qr[hd];
      float4 c_0 = Cb4[(hd * 128 + c0) >> 2];
      float4 c_1 = Cb4[((hd * 128 + c0) >> 2) + 1];
      s0.x += qv * c_0.x; s0.y += qv * c_0.y; s0.z += qv * c_0.z; s0.w += qv * c_0.w;
      s1.x += qv * c_1.x; s1.y += qv * c_1.y; s1.z += qv * c_1.z; s1.w += qv * c_1.w;
    }
    Zs[r * 129 + c0 + 0] = s0.x + b_out[c0 + 0];
    Zs[r * 129 + c0 + 1] = s0.y + b_out[c0 + 1];
    Zs[r * 129 + c0 + 2] = s0.z + b_out[c0 + 2];
    Zs[r * 129 + c0 + 3] = s0.w + b_out[c0 + 3];
    Zs[r * 129 + c0 + 4] = s1.x + b_out[c0 + 4];
    Zs[r * 129 + c0 + 5] = s1.y + b_out[c0 + 5];
    Zs[r * 129 + c0 + 6] = s1.z + b_out[c0 + 6];
    Zs[r * 129 + c0 + 7] = s1.w + b_out[c0 + 7];
  }
  __syncthreads();
  {   // LayerNorm over c, 4 threads/row
    const int row = tid >> 2, q4 = tid & 3;
    const float* zr = Zs + row * 129 + q4 * 32;
    float vals[32], s = 0.f, ss = 0.f;
    #pragma unroll
    for (int j = 0; j < 32; ++j) {
      float v = zr[j];
      vals[j] = v; s += v; ss += v * v;
    }
    s += __shfl_xor(s, 1);  ss += __shfl_xor(ss, 1);
    s += __shfl_xor(s, 2);  ss += __shfl_xor(ss, 2);
    const float mean = s * (1.f / 128.f);
    const float var  = ss * (1.f / 128.f) - mean * mean;
    const float rstd = rsqrtf(var + 1e-5f);
    float* dst = outg + (row0 + row) * 128 + q4 * 32;
    #pragma unroll
    for (int j = 0; j < 32; ++j)
      dst[j] = (vals[j] - mean) * rstd * g_ln[q4 * 32 + j] + b_ln[q4 * 32 + j];
  }
}

extern "C" void kernel_launch(void* const* d_in, const int* in_sizes, int n_in,
                              void* d_out, int out_size, void* d_ws, size_t ws_size,
                              hipStream_t stream) {
  const float* x     = (const float*)d_in[0];
  const float* w_qkv = (const float*)d_in[1];
  const float* w_out = (const float*)d_in[2];
  const float* b_out = (const float*)d_in[3];
  const float* g_ln  = (const float*)d_in[4];
  const float* b_ln  = (const float*)d_in[5];
  char* ws = (char*)d_ws;
  // ws: ctx f32 [16][4][32][32] @0 (262144); denom f32 [16][128] @262144 (8192)
  //     Cb f32 [16][128][128] @270336 (4194304); WT f32 [384][128] @4464640 (196608)
  float* ctx   = (float*)ws;
  float* denom = (float*)(ws + 262144);
  float* Cb    = (float*)(ws + 270336);
  float* WT    = (float*)(ws + 4464640);
  float* outp  = (float*)d_out;

  hipLaunchKernelGGL(kinit_f32, dim3(128), dim3(256), 0, stream, w_qkv, WT, ctx, 67584);
  hipLaunchKernelGGL(k1kv_f32, dim3(4096), dim3(256), 0, stream, x, WT, ctx, denom);
  hipLaunchKernelGGL(k2_f32,   dim3(16),   dim3(256), 0, stream, ctx, denom, w_out, Cb);
  hipLaunchKernelGGL(k3_f32,   dim3(4096), dim3(256), 0, stream, x, WT, Cb,
                     b_out, g_ln, b_ln, outp);
}

// Round 6
// 3172.707 us; speedup vs baseline: 3.6424x; 3.6424x over previous
//
#include <hip/hip_runtime.h>

// Round 6: single-variable bisection. k1kv = r5's MFMA version (device under test).
// Everything else = r4-verified fp32 verbatim (k2_f32, k3_f32 serial, fp32 Cb).
// kinit emits both fp32 WT (k3) and hi/lo bf16 WT (k1kv).

#define SCALE 0.17677669529663687f

typedef __attribute__((ext_vector_type(8))) short bf16x8;
typedef __attribute__((ext_vector_type(4))) float f32x4;
typedef unsigned short ushort_t;

__device__ __forceinline__ unsigned int f2bf(float f) {
  unsigned int u = __float_as_uint(f);
  return (u + 0x7FFFu + ((u >> 16) & 1u)) >> 16;   // RNE f32 -> bf16 bits
}
__device__ __forceinline__ float bf2f(unsigned short s) {
  return __uint_as_float(((unsigned int)s) << 16);
}

__device__ __forceinline__ void pack_hilo(const float* __restrict__ f, int4& vh, int4& vl) {
  unsigned int h[8], lo[8];
  #pragma unroll
  for (int j = 0; j < 8; ++j) {
    h[j] = f2bf(f[j]);
    lo[j] = f2bf(f[j] - bf2f((unsigned short)h[j]));
  }
  vh.x = (int)(h[0] | (h[1] << 16));  vh.y = (int)(h[2] | (h[3] << 16));
  vh.z = (int)(h[4] | (h[5] << 16));  vh.w = (int)(h[6] | (h[7] << 16));
  vl.x = (int)(lo[0] | (lo[1] << 16)); vl.y = (int)(lo[2] | (lo[3] << 16));
  vl.z = (int)(lo[4] | (lo[5] << 16)); vl.w = (int)(lo[6] | (lo[7] << 16));
}

// ---------- init: zero ctx+denom; WT fp32 [384][128]; WTh/WTl bf16 [384][128]
__global__ void kinit(const float* __restrict__ w_qkv, float* __restrict__ WT,
                      ushort_t* __restrict__ WTh, ushort_t* __restrict__ WTl,
                      float* __restrict__ zero_region, int nzero) {
  int i = blockIdx.x * blockDim.x + threadIdx.x;
  int stride = gridDim.x * blockDim.x;
  for (int j = i; j < nzero; j += stride) zero_region[j] = 0.0f;
  for (int j = i; j < 384 * 128; j += stride) {
    int f = j >> 7, c = j & 127;
    float wv = w_qkv[c * 384 + f];
    WT[j] = wv;
    unsigned int h = f2bf(wv);
    WTh[j] = (ushort_t)h;
    WTl[j] = (ushort_t)f2bf(wv - bf2f((unsigned short)h));
  }
}

// ---------- k1kv: r5's MFMA version, verbatim (DEVICE UNDER TEST)
__global__ __launch_bounds__(256) void k1kv(const float* __restrict__ xg,
                                            const ushort_t* __restrict__ WTh,
                                            const ushort_t* __restrict__ WTl,
                                            float* __restrict__ ctx,
                                            float* __restrict__ denom) {
  __shared__ __align__(16) char smem[65536];
  short* Ah = (short*)smem;             // [64][136] bf16 x hi (staging phase)
  short* Al = (short*)(smem + 17408);   // [64][136] bf16 x lo
  float* Ek = (float*)smem;             // overlay: [64][128] fp32 exp(k)
  float* Vs = (float*)(smem + 32768);   // overlay: [64][128] fp32 v
  const int tid = threadIdx.x;
  const int row0 = blockIdx.x * 64;
  const int b = row0 >> 14;
  for (int cid = tid; cid < 1024; cid += 256) {
    int row = cid >> 4, cs = cid & 15;
    const float4* p = (const float4*)(xg + (row0 + row) * 128 + cs * 8);
    float4 a = p[0], bb = p[1];
    float f[8] = {a.x, a.y, a.z, a.w, bb.x, bb.y, bb.z, bb.w};
    int4 vh, vl;
    pack_hilo(f, vh, vl);
    *(int4*)&Ah[row * 136 + cs * 8] = vh;
    *(int4*)&Al[row * 136 + cs * 8] = vl;
  }
  __syncthreads();
  const int w = tid >> 6, l = tid & 63;   // wave w owns 64 of the 256 k|v cols
  const int lr = l & 15, lg = l >> 4;
  f32x4 acc[4][4];
  #pragma unroll
  for (int i = 0; i < 4; ++i)
    #pragma unroll
    for (int n = 0; n < 4; ++n) acc[i][n] = (f32x4){0.f, 0.f, 0.f, 0.f};
  #pragma unroll
  for (int kk = 0; kk < 4; ++kk) {
    const int k0 = kk * 32 + lg * 8;
    bf16x8 ah[4], al[4];
    #pragma unroll
    for (int i = 0; i < 4; ++i) {
      ah[i] = *(const bf16x8*)&Ah[(i * 16 + lr) * 136 + k0];
      al[i] = *(const bf16x8*)&Al[(i * 16 + lr) * 136 + k0];
    }
    #pragma unroll
    for (int n = 0; n < 4; ++n) {
      const int f = 128 + w * 64 + n * 16 + lr;   // k cols 128..255, v cols 256..383
      bf16x8 bh = *(const bf16x8*)(WTh + f * 128 + k0);
      bf16x8 bl = *(const bf16x8*)(WTl + f * 128 + k0);
      #pragma unroll
      for (int i = 0; i < 4; ++i) {
        acc[i][n] = __builtin_amdgcn_mfma_f32_16x16x32_bf16(ah[i], bh, acc[i][n], 0, 0, 0);
        acc[i][n] = __builtin_amdgcn_mfma_f32_16x16x32_bf16(ah[i], bl, acc[i][n], 0, 0, 0);
        acc[i][n] = __builtin_amdgcn_mfma_f32_16x16x32_bf16(al[i], bh, acc[i][n], 0, 0, 0);
      }
    }
  }
  __syncthreads();   // Ah/Al reads done; overlay with fp32 Ek/Vs
  {
    float* T = (w < 2) ? Ek : Vs;
    const int cb = (w & 1) * 64;
    #pragma unroll
    for (int i = 0; i < 4; ++i)
      #pragma unroll
      for (int n = 0; n < 4; ++n)
        #pragma unroll
        for (int r = 0; r < 4; ++r) {
          int rr = i * 16 + lg * 4 + r;
          int col = cb + n * 16 + lr;
          float vv = acc[i][n][r];
          T[rr * 128 + col] = (w < 2) ? __expf(vv) : vv;  // |k|<~6: exp fp32-safe
        }
  }
  __syncthreads();
  // r4-verified serial fp32 outer product: thread = (head h, d, e-half)
  const int h = tid >> 6, rem = tid & 63, d = rem >> 1, eh = rem & 1;
  const int kcol = h * 32 + d, vc = h * 32 + eh * 16;
  float4 c0 = {0.f,0.f,0.f,0.f}, c1 = c0, c2 = c0, c3 = c0;
  float dsum = 0.f;
  for (int rr = 0; rr < 64; ++rr) {
    float ekv = Ek[rr * 128 + kcol];
    dsum += ekv;
    const float4* vp = (const float4*)&Vs[rr * 128 + vc];
    float4 v0 = vp[0], v1 = vp[1], v2 = vp[2], v3 = vp[3];
    c0.x += ekv * v0.x; c0.y += ekv * v0.y; c0.z += ekv * v0.z; c0.w += ekv * v0.w;
    c1.x += ekv * v1.x; c1.y += ekv * v1.y; c1.z += ekv * v1.z; c1.w += ekv * v1.w;
    c2.x += ekv * v2.x; c2.y += ekv * v2.y; c2.z += ekv * v2.z; c2.w += ekv * v2.w;
    c3.x += ekv * v3.x; c3.y += ekv * v3.y; c3.z += ekv * v3.z; c3.w += ekv * v3.w;
  }
  float* cdst = ctx + ((b * 4 + h) * 32 + d) * 32 + eh * 16;
  float cf[16] = {c0.x,c0.y,c0.z,c0.w, c1.x,c1.y,c1.z,c1.w,
                  c2.x,c2.y,c2.z,c2.w, c3.x,c3.y,c3.z,c3.w};
  #pragma unroll
  for (int j = 0; j < 16; ++j) atomicAdd(cdst + j, cf[j]);
  if (eh == 0) atomicAdd(denom + b * 128 + kcol, dsum);
}

// ---------- k2: r4 verbatim (fp32 Cb)
__global__ __launch_bounds__(256) void k2_f32(const float* __restrict__ ctx,
                                              const float* __restrict__ denom,
                                              const float* __restrict__ w_out,
                                              float* __restrict__ Cb) {
  __shared__ float c2[128][33];
  const int b = blockIdx.x, tid = threadIdx.x;
  for (int i = tid; i < 4096; i += 256) {
    int hd = i >> 5, e = i & 31;
    c2[hd][e] = SCALE * ctx[b * 4096 + i] / denom[b * 128 + hd];
  }
  __syncthreads();
  for (int o = tid; o < 16384; o += 256) {
    int hd = o >> 7, cc = o & 127, h = hd >> 5;
    float sacc = 0.f;
    #pragma unroll
    for (int e = 0; e < 32; ++e)
      sacc += c2[hd][e] * w_out[(h * 32 + e) * 128 + cc];
    Cb[b * 16384 + hd * 128 + cc] = sacc;
  }
}

// ---------- k3: r4 verbatim (fp32 serial GEMMs + exact softmax + LN)
__global__ __launch_bounds__(256, 2) void k3_f32(const float* __restrict__ xg,
                                                 const float* __restrict__ WT,
                                                 const float* __restrict__ Cb,
                                                 const float* __restrict__ b_out,
                                                 const float* __restrict__ g_ln,
                                                 const float* __restrict__ b_ln,
                                                 float* __restrict__ outg) {
  __shared__ __align__(16) float xs[64 * 132];
  __shared__ float Qs[64 * 129];   // later overlaid as Zs
  const int tid = threadIdx.x;
  const int row0 = blockIdx.x * 64;
  const int b = row0 >> 14;
  float4* xs4 = (float4*)xs;
  const float4* xg4 = (const float4*)xg;
  const float4* WT4 = (const float4*)WT;
  const float4* Cb4 = (const float4*)(Cb + b * 16384);
  for (int i = tid; i < 2048; i += 256) {
    int row = i >> 5, c4 = i & 31;
    xs4[row * 33 + c4] = xg4[(row0 + row) * 32 + c4];
  }
  __syncthreads();
  const int r = tid & 63, fgrp = tid >> 6;
  {
    float4 xr4[32];
    #pragma unroll 32
    for (int c4 = 0; c4 < 32; ++c4) xr4[c4] = xs4[r * 33 + c4];
    for (int p = 0; p < 4; ++p) {
      float acc[8];
      #pragma unroll
      for (int u = 0; u < 8; ++u) acc[u] = 0.f;
      const int fb = fgrp * 32 + p * 8;         // q cols 0..127
      #pragma unroll 32
      for (int c4 = 0; c4 < 32; ++c4) {
        float4 xv = xr4[c4];
        #pragma unroll
        for (int u = 0; u < 8; ++u) {
          float4 wv = WT4[(fb + u) * 32 + c4];
          acc[u] += xv.x * wv.x + xv.y * wv.y + xv.z * wv.z + xv.w * wv.w;
        }
      }
      #pragma unroll
      for (int u = 0; u < 8; ++u) Qs[r * 129 + fb + u] = acc[u];
    }
  }
  __syncthreads();
  {   // exact softmax over d per (row, head): thread owns one (row, head)
    const int row = tid >> 2, hh = tid & 3;
    const int base = row * 129 + hh * 32;
    float e[32], m = -1e30f;
    #pragma unroll
    for (int j = 0; j < 32; ++j) { e[j] = Qs[base + j]; m = fmaxf(m, e[j]); }
    float s = 0.f;
    #pragma unroll
    for (int j = 0; j < 32; ++j) { e[j] = expf(e[j] - m); s += e[j]; }
    float inv = 1.0f / s;
    #pragma unroll
    for (int j = 0; j < 32; ++j) Qs[base + j] = e[j] * inv;   // no scale (in Cb)
  }
  __syncthreads();
  float qr[128];
  #pragma unroll 128
  for (int j = 0; j < 128; ++j) qr[j] = Qs[r * 129 + j];
  __syncthreads();   // all Qs reads done before Zs overlay
  float* Zs = Qs;
  for (int p = 0; p < 4; ++p) {
    const int c0 = fgrp * 32 + p * 8;
    float4 s0 = {0.f, 0.f, 0.f, 0.f}, s1 = {0.f, 0.f, 0.f, 0.f};
    #pragma unroll 128
    for (int hd = 0; hd < 128; ++hd) {
      float qv = qr[hd];
      float4 c_0 = Cb4[(hd * 128 + c0) >> 2];
      float4 c_1 = Cb4[((hd * 128 + c0) >> 2) + 1];
      s0.x += qv * c_0.x; s0.y += qv * c_0.y; s0.z += qv * c_0.z; s0.w += qv * c_0.w;
      s1.x += qv * c_1.x; s1.y += qv * c_1.y; s1.z += qv * c_1.z; s1.w += qv * c_1.w;
    }
    Zs[r * 129 + c0 + 0] = s0.x + b_out[c0 + 0];
    Zs[r * 129 + c0 + 1] = s0.y + b_out[c0 + 1];
    Zs[r * 129 + c0 + 2] = s0.z + b_out[c0 + 2];
    Zs[r * 129 + c0 + 3] = s0.w + b_out[c0 + 3];
    Zs[r * 129 + c0 + 4] = s1.x + b_out[c0 + 4];
    Zs[r * 129 + c0 + 5] = s1.y + b_out[c0 + 5];
    Zs[r * 129 + c0 + 6] = s1.z + b_out[c0 + 6];
    Zs[r * 129 + c0 + 7] = s1.w + b_out[c0 + 7];
  }
  __syncthreads();
  {   // LayerNorm over c, 4 threads/row
    const int row = tid >> 2, q4 = tid & 3;
    const float* zr = Zs + row * 129 + q4 * 32;
    float vals[32], s = 0.f, ss = 0.f;
    #pragma unroll
    for (int j = 0; j < 32; ++j) {
      float v = zr[j];
      vals[j] = v; s += v; ss += v * v;
    }
    s += __shfl_xor(s, 1);  ss += __shfl_xor(ss, 1);
    s += __shfl_xor(s, 2);  ss += __shfl_xor(ss, 2);
    const float mean = s * (1.f / 128.f);
    const float var  = ss * (1.f / 128.f) - mean * mean;
    const float rstd = rsqrtf(var + 1e-5f);
    float* dst = outg + (row0 + row) * 128 + q4 * 32;
    #pragma unroll
    for (int j = 0; j < 32; ++j)
      dst[j] = (vals[j] - mean) * rstd * g_ln[q4 * 32 + j] + b_ln[q4 * 32 + j];
  }
}

extern "C" void kernel_launch(void* const* d_in, const int* in_sizes, int n_in,
                              void* d_out, int out_size, void* d_ws, size_t ws_size,
                              hipStream_t stream) {
  const float* x     = (const float*)d_in[0];
  const float* w_qkv = (const float*)d_in[1];
  const float* w_out = (const float*)d_in[2];
  const float* b_out = (const float*)d_in[3];
  const float* g_ln  = (const float*)d_in[4];
  const float* b_ln  = (const float*)d_in[5];
  char* ws = (char*)d_ws;
  // ws: ctx f32 @0 (262144); denom f32 @262144 (8192); Cb f32 @270336 (4194304)
  //     WT f32 @4464640 (196608); WTh @4661248 (98304); WTl @4759552 (98304)
  float*    ctx   = (float*)ws;
  float*    denom = (float*)(ws + 262144);
  float*    Cb    = (float*)(ws + 270336);
  float*    WT    = (float*)(ws + 4464640);
  ushort_t* WTh   = (ushort_t*)(ws + 4661248);
  ushort_t* WTl   = (ushort_t*)(ws + 4759552);
  float* outp = (float*)d_out;

  hipLaunchKernelGGL(kinit, dim3(128), dim3(256), 0, stream, w_qkv, WT, WTh, WTl, ctx, 67584);
  hipLaunchKernelGGL(k1kv, dim3(4096), dim3(256), 0, stream, x, WTh, WTl, ctx, denom);
  hipLaunchKernelGGL(k2_f32, dim3(16), dim3(256), 0, stream, ctx, denom, w_out, Cb);
  hipLaunchKernelGGL(k3_f32, dim3(4096), dim3(256), 0, stream, x, WT, Cb,
                     b_out, g_ln, b_ln, outp);
}

// Round 12
// 1355.582 us; speedup vs baseline: 8.5249x; 2.3405x over previous
//
#include <hip/hip_runtime.h>

// Round 11 RESUBMIT (container died; no data last round). Bisect r10's two
// simultaneous changes.
//   KEEP: r10's deterministic k1kv (partials) + kred (fixed-order reduce).
//   REVERT: k3 back to r9's k3_hyb VERBATIM (serial fp32 GEMM-1 + exact softmax
//           + staged hi/lo qsm + MFMA GEMM-2) - passed first validation in r9.
// kinit emits fp32 WT (serial GEMM-1) + hi/lo WTh/WTl (k1kv).

#define SCALE 0.17677669529663687f

typedef __attribute__((ext_vector_type(8))) short bf16x8;
typedef __attribute__((ext_vector_type(4))) float f32x4;
typedef unsigned short ushort_t;

__device__ __forceinline__ unsigned int f2bf(float f) {
  unsigned int u = __float_as_uint(f);
  return (u + 0x7FFFu + ((u >> 16) & 1u)) >> 16;   // RNE f32 -> bf16 bits
}
__device__ __forceinline__ float bf2f(unsigned short s) {
  return __uint_as_float(((unsigned int)s) << 16);
}

__device__ __forceinline__ void pack_hilo(const float* __restrict__ f, int4& vh, int4& vl) {
  unsigned int h[8], lo[8];
  #pragma unroll
  for (int j = 0; j < 8; ++j) {
    h[j] = f2bf(f[j]);
    lo[j] = f2bf(f[j] - bf2f((unsigned short)h[j]));
  }
  vh.x = (int)(h[0] | (h[1] << 16));  vh.y = (int)(h[2] | (h[3] << 16));
  vh.z = (int)(h[4] | (h[5] << 16));  vh.w = (int)(h[6] | (h[7] << 16));
  vl.x = (int)(lo[0] | (lo[1] << 16)); vl.y = (int)(lo[2] | (lo[3] << 16));
  vl.z = (int)(lo[4] | (lo[5] << 16)); vl.w = (int)(lo[6] | (lo[7] << 16));
}

// ---------- init: WT fp32 [384][128]; WTh/WTl bf16 [384][128]
__global__ void kinit(const float* __restrict__ w_qkv, float* __restrict__ WT,
                      ushort_t* __restrict__ WTh, ushort_t* __restrict__ WTl) {
  int i = blockIdx.x * blockDim.x + threadIdx.x;
  int stride = gridDim.x * blockDim.x;
  for (int j = i; j < 384 * 128; j += stride) {
    int f = j >> 7, c = j & 127;
    float wv = w_qkv[c * 384 + f];
    WT[j] = wv;
    unsigned int h = f2bf(wv);
    WTh[j] = (ushort_t)h;
    WTl[j] = (ushort_t)f2bf(wv - bf2f((unsigned short)h));
  }
}

// ---------- k1kv: r10's deterministic version (partials out, no atomics)
__global__ __launch_bounds__(256) void k1kv(const float* __restrict__ xg,
                                            const ushort_t* __restrict__ WTh,
                                            const ushort_t* __restrict__ WTl,
                                            float* __restrict__ pctx,
                                            float* __restrict__ pden) {
  __shared__ __align__(16) char smem[65536];
  short* Ah = (short*)smem;             // [64][136] staging phase
  short* Al = (short*)(smem + 17408);
  float* Ek = (float*)smem;             // overlay: [64][128] fp32 exp(k)
  float* Vs = (float*)(smem + 32768);   // overlay: [64][128] fp32 v
  const int tid = threadIdx.x;
  const int w = tid >> 6, l = tid & 63;
  const int lr = l & 15, lg = l >> 4;
  const int rem = tid & 63, d = rem >> 1, eh = rem & 1;   // head h == w
  const int kcol = w * 32 + d, vc = w * 32 + eh * 16;
  float4 c0 = {0.f,0.f,0.f,0.f}, c1 = c0, c2 = c0, c3 = c0;
  float dsum = 0.f;
  for (int t = 0; t < 2; ++t) {
    const int row0 = blockIdx.x * 128 + t * 64;
    for (int cid = tid; cid < 1024; cid += 256) {
      int row = cid >> 4, cs = cid & 15;
      const float4* p = (const float4*)(xg + (row0 + row) * 128 + cs * 8);
      float4 a = p[0], bb = p[1];
      float f[8] = {a.x, a.y, a.z, a.w, bb.x, bb.y, bb.z, bb.w};
      int4 vh, vl;
      pack_hilo(f, vh, vl);
      *(int4*)&Ah[row * 136 + cs * 8] = vh;
      *(int4*)&Al[row * 136 + cs * 8] = vl;
    }
    __syncthreads();
    f32x4 acc[4][4];
    #pragma unroll
    for (int i = 0; i < 4; ++i)
      #pragma unroll
      for (int n = 0; n < 4; ++n) acc[i][n] = (f32x4){0.f, 0.f, 0.f, 0.f};
    #pragma unroll
    for (int kk = 0; kk < 4; ++kk) {
      const int k0 = kk * 32 + lg * 8;
      bf16x8 ah[4], al[4];
      #pragma unroll
      for (int i = 0; i < 4; ++i) {
        ah[i] = *(const bf16x8*)&Ah[(i * 16 + lr) * 136 + k0];
        al[i] = *(const bf16x8*)&Al[(i * 16 + lr) * 136 + k0];
      }
      #pragma unroll
      for (int n = 0; n < 4; ++n) {
        const int f = 128 + w * 64 + n * 16 + lr;   // k cols 128..255, v 256..383
        bf16x8 bh = *(const bf16x8*)(WTh + f * 128 + k0);
        bf16x8 bl = *(const bf16x8*)(WTl + f * 128 + k0);
        #pragma unroll
        for (int i = 0; i < 4; ++i) {
          acc[i][n] = __builtin_amdgcn_mfma_f32_16x16x32_bf16(ah[i], bh, acc[i][n], 0, 0, 0);
          acc[i][n] = __builtin_amdgcn_mfma_f32_16x16x32_bf16(ah[i], bl, acc[i][n], 0, 0, 0);
          acc[i][n] = __builtin_amdgcn_mfma_f32_16x16x32_bf16(al[i], bh, acc[i][n], 0, 0, 0);
        }
      }
    }
    __syncthreads();   // Ah/Al reads done; overlay with fp32 Ek/Vs
    {
      float* T = (w < 2) ? Ek : Vs;
      const int cb = (w & 1) * 64;
      #pragma unroll
      for (int i = 0; i < 4; ++i)
        #pragma unroll
        for (int n = 0; n < 4; ++n)
          #pragma unroll
          for (int r = 0; r < 4; ++r) {
            int rr = i * 16 + lg * 4 + r;
            int col = cb + n * 16 + lr;
            float vv = acc[i][n][r];
            T[rr * 128 + col] = (w < 2) ? __expf(vv) : vv;  // |k|<~6: fp32-safe
          }
    }
    __syncthreads();
    for (int rr = 0; rr < 64; ++rr) {
      float ekv = Ek[rr * 128 + kcol];
      dsum += ekv;
      const float4* vp = (const float4*)&Vs[rr * 128 + vc];
      float4 v0 = vp[0], v1 = vp[1], v2 = vp[2], v3 = vp[3];
      c0.x += ekv * v0.x; c0.y += ekv * v0.y; c0.z += ekv * v0.z; c0.w += ekv * v0.w;
      c1.x += ekv * v1.x; c1.y += ekv * v1.y; c1.z += ekv * v1.z; c1.w += ekv * v1.w;
      c2.x += ekv * v2.x; c2.y += ekv * v2.y; c2.z += ekv * v2.z; c2.w += ekv * v2.w;
      c3.x += ekv * v3.x; c3.y += ekv * v3.y; c3.z += ekv * v3.z; c3.w += ekv * v3.w;
    }
    __syncthreads();   // Ek/Vs reads done before next tile's staging overwrites
  }
  float cf[16] = {c0.x,c0.y,c0.z,c0.w, c1.x,c1.y,c1.z,c1.w,
                  c2.x,c2.y,c2.z,c2.w, c3.x,c3.y,c3.z,c3.w};
  float* pdst = pctx + blockIdx.x * 4096 + (w * 32 + d) * 32 + eh * 16;
  #pragma unroll
  for (int j = 0; j < 16; ++j) pdst[j] = cf[j];
  if (eh == 0) pden[blockIdx.x * 128 + kcol] = dsum;
}

// ---------- kred: fixed-order reduction of partials (deterministic)
__global__ __launch_bounds__(256) void kred(const float* __restrict__ pctx,
                                            const float* __restrict__ pden,
                                            float* __restrict__ ctx,
                                            float* __restrict__ denom) {
  const int bb = blockIdx.x;            // 256 blocks: 16 segs x 16 batches
  const int b = bb >> 4, seg = bb & 15;
  const int i = seg * 256 + threadIdx.x;   // 0..4095
  float s = 0.f;
  const float* src = pctx + (size_t)(b * 128) * 4096 + i;
  for (int p = 0; p < 128; ++p) s += src[(size_t)p * 4096];
  ctx[b * 4096 + i] = s;
  if (seg == 0 && threadIdx.x < 128) {
    float sd = 0.f;
    const float* sp = pden + (b * 128) * 128 + threadIdx.x;
    for (int p = 0; p < 128; ++p) sd += sp[p * 128];
    denom[b * 128 + threadIdx.x] = sd;
  }
}

// ---------- k2: r9 verbatim (r4 math, hi/lo transposed CmT emission)
__global__ __launch_bounds__(256) void k2(const float* __restrict__ ctx,
                                          const float* __restrict__ denom,
                                          const float* __restrict__ w_out,
                                          ushort_t* __restrict__ CmTh,
                                          ushort_t* __restrict__ CmTl) {
  __shared__ float c2s[128][33];
  const int b = blockIdx.x, tid = threadIdx.x;
  for (int i = tid; i < 4096; i += 256) {
    int hd = i >> 5, e = i & 31;
    c2s[hd][e] = SCALE * ctx[b * 4096 + i] / denom[b * 128 + hd];
  }
  __syncthreads();
  for (int o = tid; o < 16384; o += 256) {
    int hd = o >> 7, cc = o & 127, h = hd >> 5;
    float sacc = 0.f;
    #pragma unroll
    for (int e = 0; e < 32; ++e)
      sacc += c2s[hd][e] * w_out[(h * 32 + e) * 128 + cc];
    unsigned int hh = f2bf(sacc);
    CmTh[b * 16384 + cc * 128 + hd] = (ushort_t)hh;
    CmTl[b * 16384 + cc * 128 + hd] = (ushort_t)f2bf(sacc - bf2f((unsigned short)hh));
  }
}

// ---------- k3: r9's k3_hyb VERBATIM (passed first validation at 0.0156)
__global__ __launch_bounds__(256, 2) void k3_hyb(const float* __restrict__ xg,
                                                 const float* __restrict__ WT,
                                                 const ushort_t* __restrict__ CmTh,
                                                 const ushort_t* __restrict__ CmTl,
                                                 const float* __restrict__ b_out,
                                                 const float* __restrict__ g_ln,
                                                 const float* __restrict__ b_ln,
                                                 float* __restrict__ outg) {
  __shared__ __align__(16) char smem[67840];
  float* Qs = (float*)smem;              // [64*129] fp32 q / qsm / (later) Zs
  float* xs = (float*)(smem + 33024);    // [64*132] fp32 x staging (GEMM-1)
  short* QAh = (short*)(smem + 33024);   // overlay after GEMM-1: [64][136] bf16 q hi
  short* QAl = (short*)(smem + 50432);   // [64][136] bf16 q lo
  const int tid = threadIdx.x;
  const int row0 = blockIdx.x * 64;
  const int b = row0 >> 14;
  float4* xs4 = (float4*)xs;
  const float4* xg4 = (const float4*)xg;
  const float4* WT4 = (const float4*)WT;
  for (int i = tid; i < 2048; i += 256) {
    int row = i >> 5, c4 = i & 31;
    xs4[row * 33 + c4] = xg4[(row0 + row) * 32 + c4];
  }
  __syncthreads();
  const int r = tid & 63, fgrp = tid >> 6;
  {
    float4 xr4[32];
    #pragma unroll 32
    for (int c4 = 0; c4 < 32; ++c4) xr4[c4] = xs4[r * 33 + c4];
    for (int p = 0; p < 4; ++p) {
      float acc[8];
      #pragma unroll
      for (int u = 0; u < 8; ++u) acc[u] = 0.f;
      const int fb = fgrp * 32 + p * 8;         // q cols 0..127
      #pragma unroll 32
      for (int c4 = 0; c4 < 32; ++c4) {
        float4 xv = xr4[c4];
        #pragma unroll
        for (int u = 0; u < 8; ++u) {
          float4 wv = WT4[(fb + u) * 32 + c4];
          acc[u] += xv.x * wv.x + xv.y * wv.y + xv.z * wv.z + xv.w * wv.w;
        }
      }
      #pragma unroll
      for (int u = 0; u < 8; ++u) Qs[r * 129 + fb + u] = acc[u];
    }
  }
  __syncthreads();
  {   // exact softmax over d per (row, head)
    const int row = tid >> 2, hh = tid & 3;
    const int base = row * 129 + hh * 32;
    float e[32], m = -1e30f;
    #pragma unroll
    for (int j = 0; j < 32; ++j) { e[j] = Qs[base + j]; m = fmaxf(m, e[j]); }
    float s = 0.f;
    #pragma unroll
    for (int j = 0; j < 32; ++j) { e[j] = expf(e[j] - m); s += e[j]; }
    float inv = 1.0f / s;
    #pragma unroll
    for (int j = 0; j < 32; ++j) Qs[base + j] = e[j] * inv;
  }
  __syncthreads();   // xs dead from here; stage qsm -> QAh/QAl (k1kv idiom)
  for (int cid = tid; cid < 1024; cid += 256) {
    int row = cid >> 4, cs = cid & 15;
    float f[8];
    #pragma unroll
    for (int j = 0; j < 8; ++j) f[j] = Qs[row * 129 + cs * 8 + j];
    int4 vh, vl;
    pack_hilo(f, vh, vl);
    *(int4*)&QAh[row * 136 + cs * 8] = vh;
    *(int4*)&QAl[row * 136 + cs * 8] = vl;
  }
  __syncthreads();
  // ---- MFMA GEMM-2: k1kv tiling, staged bf16x8 A-path, B = hi/lo CmT
  const int w = tid >> 6, l = tid & 63;
  const int lr = l & 15, lg = l >> 4;
  const ushort_t* Bh = CmTh + b * 16384;
  const ushort_t* Bl = CmTl + b * 16384;
  f32x4 acc2[4][2];
  #pragma unroll
  for (int i = 0; i < 4; ++i)
    #pragma unroll
    for (int n = 0; n < 2; ++n) acc2[i][n] = (f32x4){0.f, 0.f, 0.f, 0.f};
  #pragma unroll
  for (int kk = 0; kk < 4; ++kk) {
    const int k0 = kk * 32 + lg * 8;
    bf16x8 qh[4], ql[4];
    #pragma unroll
    for (int i = 0; i < 4; ++i) {
      qh[i] = *(const bf16x8*)&QAh[(i * 16 + lr) * 136 + k0];
      ql[i] = *(const bf16x8*)&QAl[(i * 16 + lr) * 136 + k0];
    }
    #pragma unroll
    for (int n = 0; n < 2; ++n) {
      const int cc = w * 32 + n * 16 + lr;
      bf16x8 bh = *(const bf16x8*)(Bh + cc * 128 + k0);
      bf16x8 bl = *(const bf16x8*)(Bl + cc * 128 + k0);
      #pragma unroll
      for (int i = 0; i < 4; ++i) {
        acc2[i][n] = __builtin_amdgcn_mfma_f32_16x16x32_bf16(qh[i], bh, acc2[i][n], 0, 0, 0);
        acc2[i][n] = __builtin_amdgcn_mfma_f32_16x16x32_bf16(qh[i], bl, acc2[i][n], 0, 0, 0);
        acc2[i][n] = __builtin_amdgcn_mfma_f32_16x16x32_bf16(ql[i], bh, acc2[i][n], 0, 0, 0);
      }
    }
  }
  __syncthreads();   // Qs reads done (staging copied it); overlay with Zs
  float* Zs = Qs;
  #pragma unroll
  for (int i = 0; i < 4; ++i)
    #pragma unroll
    for (int n = 0; n < 2; ++n) {
      const int cc = w * 32 + n * 16 + lr;
      #pragma unroll
      for (int rr2 = 0; rr2 < 4; ++rr2) {
        int rr = i * 16 + lg * 4 + rr2;
        Zs[rr * 129 + cc] = acc2[i][n][rr2] + b_out[cc];
      }
    }
  __syncthreads();
  {   // LayerNorm over c, 4 threads/row (r4-verified)
    const int row = tid >> 2, q4 = tid & 3;
    const float* zr = Zs + row * 129 + q4 * 32;
    float vals[32], s = 0.f, ss = 0.f;
    #pragma unroll
    for (int j = 0; j < 32; ++j) {
      float v = zr[j];
      vals[j] = v; s += v; ss += v * v;
    }
    s += __shfl_xor(s, 1);  ss += __shfl_xor(ss, 1);
    s += __shfl_xor(s, 2);  ss += __shfl_xor(ss, 2);
    const float mean = s * (1.f / 128.f);
    const float var  = ss * (1.f / 128.f) - mean * mean;
    const float rstd = rsqrtf(var + 1e-5f);
    float* dst = outg + (row0 + row) * 128 + q4 * 32;
    #pragma unroll
    for (int j = 0; j < 32; ++j)
      dst[j] = (vals[j] - mean) * rstd * g_ln[q4 * 32 + j] + b_ln[q4 * 32 + j];
  }
}

extern "C" void kernel_launch(void* const* d_in, const int* in_sizes, int n_in,
                              void* d_out, int out_size, void* d_ws, size_t ws_size,
                              hipStream_t stream) {
  const float* x     = (const float*)d_in[0];
  const float* w_qkv = (const float*)d_in[1];
  const float* w_out = (const float*)d_in[2];
  const float* b_out = (const float*)d_in[3];
  const float* g_ln  = (const float*)d_in[4];
  const float* b_ln  = (const float*)d_in[5];
  char* ws = (char*)d_ws;
  // ws: ctx @0 (262144); denom @262144 (8192); CmTh @270336 (524288);
  //     CmTl @794624 (524288); WT f32 @1318912 (196608); WTh @1515520 (98304);
  //     WTl @1613824 (98304); pctx @1712128 (33554432); pden @35266560 (1048576)
  float*    ctx   = (float*)ws;
  float*    denom = (float*)(ws + 262144);
  ushort_t* CmTh  = (ushort_t*)(ws + 270336);
  ushort_t* CmTl  = (ushort_t*)(ws + 794624);
  float*    WT    = (float*)(ws + 1318912);
  ushort_t* WTh   = (ushort_t*)(ws + 1515520);
  ushort_t* WTl   = (ushort_t*)(ws + 1613824);
  float*    pctx  = (float*)(ws + 1712128);
  float*    pden  = (float*)(ws + 35266560);
  float* outp = (float*)d_out;

  hipLaunchKernelGGL(kinit, dim3(64),   dim3(256), 0, stream, w_qkv, WT, WTh, WTl);
  hipLaunchKernelGGL(k1kv,  dim3(2048), dim3(256), 0, stream, x, WTh, WTl, pctx, pden);
  hipLaunchKernelGGL(kred,  dim3(256),  dim3(256), 0, stream, pctx, pden, ctx, denom);
  hipLaunchKernelGGL(k2,    dim3(16),   dim3(256), 0, stream, ctx, denom, w_out, CmTh, CmTl);
  hipLaunchKernelGGL(k3_hyb, dim3(4096), dim3(256), 0, stream, x, WT, CmTh, CmTl,
                     b_out, g_ln, b_ln, outp);
}

// Round 13
// 795.986 us; speedup vs baseline: 14.5180x; 1.7030x over previous
//
#include <hip/hip_runtime.h>

// Round 13: perf. r12 verbatim EXCEPT k3_hyb's serial GEMM-1 restructured to
// single-pass acc[32] (no xr4[32] register cache -> no scratch spills).
// Arithmetic bit-identical to r12's validated GEMM-1 (same per-column c4 order).

#define SCALE 0.17677669529663687f

typedef __attribute__((ext_vector_type(8))) short bf16x8;
typedef __attribute__((ext_vector_type(4))) float f32x4;
typedef unsigned short ushort_t;

__device__ __forceinline__ unsigned int f2bf(float f) {
  unsigned int u = __float_as_uint(f);
  return (u + 0x7FFFu + ((u >> 16) & 1u)) >> 16;   // RNE f32 -> bf16 bits
}
__device__ __forceinline__ float bf2f(unsigned short s) {
  return __uint_as_float(((unsigned int)s) << 16);
}

__device__ __forceinline__ void pack_hilo(const float* __restrict__ f, int4& vh, int4& vl) {
  unsigned int h[8], lo[8];
  #pragma unroll
  for (int j = 0; j < 8; ++j) {
    h[j] = f2bf(f[j]);
    lo[j] = f2bf(f[j] - bf2f((unsigned short)h[j]));
  }
  vh.x = (int)(h[0] | (h[1] << 16));  vh.y = (int)(h[2] | (h[3] << 16));
  vh.z = (int)(h[4] | (h[5] << 16));  vh.w = (int)(h[6] | (h[7] << 16));
  vl.x = (int)(lo[0] | (lo[1] << 16)); vl.y = (int)(lo[2] | (lo[3] << 16));
  vl.z = (int)(lo[4] | (lo[5] << 16)); vl.w = (int)(lo[6] | (lo[7] << 16));
}

// ---------- init: WT fp32 [384][128]; WTh/WTl bf16 [384][128]
__global__ void kinit(const float* __restrict__ w_qkv, float* __restrict__ WT,
                      ushort_t* __restrict__ WTh, ushort_t* __restrict__ WTl) {
  int i = blockIdx.x * blockDim.x + threadIdx.x;
  int stride = gridDim.x * blockDim.x;
  for (int j = i; j < 384 * 128; j += stride) {
    int f = j >> 7, c = j & 127;
    float wv = w_qkv[c * 384 + f];
    WT[j] = wv;
    unsigned int h = f2bf(wv);
    WTh[j] = (ushort_t)h;
    WTl[j] = (ushort_t)f2bf(wv - bf2f((unsigned short)h));
  }
}

// ---------- k1kv: r12-validated deterministic version (partials out, no atomics)
__global__ __launch_bounds__(256) void k1kv(const float* __restrict__ xg,
                                            const ushort_t* __restrict__ WTh,
                                            const ushort_t* __restrict__ WTl,
                                            float* __restrict__ pctx,
                                            float* __restrict__ pden) {
  __shared__ __align__(16) char smem[65536];
  short* Ah = (short*)smem;             // [64][136] staging phase
  short* Al = (short*)(smem + 17408);
  float* Ek = (float*)smem;             // overlay: [64][128] fp32 exp(k)
  float* Vs = (float*)(smem + 32768);   // overlay: [64][128] fp32 v
  const int tid = threadIdx.x;
  const int w = tid >> 6, l = tid & 63;
  const int lr = l & 15, lg = l >> 4;
  const int rem = tid & 63, d = rem >> 1, eh = rem & 1;   // head h == w
  const int kcol = w * 32 + d, vc = w * 32 + eh * 16;
  float4 c0 = {0.f,0.f,0.f,0.f}, c1 = c0, c2 = c0, c3 = c0;
  float dsum = 0.f;
  for (int t = 0; t < 2; ++t) {
    const int row0 = blockIdx.x * 128 + t * 64;
    for (int cid = tid; cid < 1024; cid += 256) {
      int row = cid >> 4, cs = cid & 15;
      const float4* p = (const float4*)(xg + (row0 + row) * 128 + cs * 8);
      float4 a = p[0], bb = p[1];
      float f[8] = {a.x, a.y, a.z, a.w, bb.x, bb.y, bb.z, bb.w};
      int4 vh, vl;
      pack_hilo(f, vh, vl);
      *(int4*)&Ah[row * 136 + cs * 8] = vh;
      *(int4*)&Al[row * 136 + cs * 8] = vl;
    }
    __syncthreads();
    f32x4 acc[4][4];
    #pragma unroll
    for (int i = 0; i < 4; ++i)
      #pragma unroll
      for (int n = 0; n < 4; ++n) acc[i][n] = (f32x4){0.f, 0.f, 0.f, 0.f};
    #pragma unroll
    for (int kk = 0; kk < 4; ++kk) {
      const int k0 = kk * 32 + lg * 8;
      bf16x8 ah[4], al[4];
      #pragma unroll
      for (int i = 0; i < 4; ++i) {
        ah[i] = *(const bf16x8*)&Ah[(i * 16 + lr) * 136 + k0];
        al[i] = *(const bf16x8*)&Al[(i * 16 + lr) * 136 + k0];
      }
      #pragma unroll
      for (int n = 0; n < 4; ++n) {
        const int f = 128 + w * 64 + n * 16 + lr;   // k cols 128..255, v 256..383
        bf16x8 bh = *(const bf16x8*)(WTh + f * 128 + k0);
        bf16x8 bl = *(const bf16x8*)(WTl + f * 128 + k0);
        #pragma unroll
        for (int i = 0; i < 4; ++i) {
          acc[i][n] = __builtin_amdgcn_mfma_f32_16x16x32_bf16(ah[i], bh, acc[i][n], 0, 0, 0);
          acc[i][n] = __builtin_amdgcn_mfma_f32_16x16x32_bf16(ah[i], bl, acc[i][n], 0, 0, 0);
          acc[i][n] = __builtin_amdgcn_mfma_f32_16x16x32_bf16(al[i], bh, acc[i][n], 0, 0, 0);
        }
      }
    }
    __syncthreads();   // Ah/Al reads done; overlay with fp32 Ek/Vs
    {
      float* T = (w < 2) ? Ek : Vs;
      const int cb = (w & 1) * 64;
      #pragma unroll
      for (int i = 0; i < 4; ++i)
        #pragma unroll
        for (int n = 0; n < 4; ++n)
          #pragma unroll
          for (int r = 0; r < 4; ++r) {
            int rr = i * 16 + lg * 4 + r;
            int col = cb + n * 16 + lr;
            float vv = acc[i][n][r];
            T[rr * 128 + col] = (w < 2) ? __expf(vv) : vv;  // |k|<~6: fp32-safe
          }
    }
    __syncthreads();
    for (int rr = 0; rr < 64; ++rr) {
      float ekv = Ek[rr * 128 + kcol];
      dsum += ekv;
      const float4* vp = (const float4*)&Vs[rr * 128 + vc];
      float4 v0 = vp[0], v1 = vp[1], v2 = vp[2], v3 = vp[3];
      c0.x += ekv * v0.x; c0.y += ekv * v0.y; c0.z += ekv * v0.z; c0.w += ekv * v0.w;
      c1.x += ekv * v1.x; c1.y += ekv * v1.y; c1.z += ekv * v1.z; c1.w += ekv * v1.w;
      c2.x += ekv * v2.x; c2.y += ekv * v2.y; c2.z += ekv * v2.z; c2.w += ekv * v2.w;
      c3.x += ekv * v3.x; c3.y += ekv * v3.y; c3.z += ekv * v3.z; c3.w += ekv * v3.w;
    }
    __syncthreads();   // Ek/Vs reads done before next tile's staging overwrites
  }
  float cf[16] = {c0.x,c0.y,c0.z,c0.w, c1.x,c1.y,c1.z,c1.w,
                  c2.x,c2.y,c2.z,c2.w, c3.x,c3.y,c3.z,c3.w};
  float* pdst = pctx + blockIdx.x * 4096 + (w * 32 + d) * 32 + eh * 16;
  #pragma unroll
  for (int j = 0; j < 16; ++j) pdst[j] = cf[j];
  if (eh == 0) pden[blockIdx.x * 128 + kcol] = dsum;
}

// ---------- kred: fixed-order reduction of partials (deterministic)
__global__ __launch_bounds__(256) void kred(const float* __restrict__ pctx,
                                            const float* __restrict__ pden,
                                            float* __restrict__ ctx,
                                            float* __restrict__ denom) {
  const int bb = blockIdx.x;            // 256 blocks: 16 segs x 16 batches
  const int b = bb >> 4, seg = bb & 15;
  const int i = seg * 256 + threadIdx.x;   // 0..4095
  float s = 0.f;
  const float* src = pctx + (size_t)(b * 128) * 4096 + i;
  for (int p = 0; p < 128; ++p) s += src[(size_t)p * 4096];
  ctx[b * 4096 + i] = s;
  if (seg == 0 && threadIdx.x < 128) {
    float sd = 0.f;
    const float* sp = pden + (b * 128) * 128 + threadIdx.x;
    for (int p = 0; p < 128; ++p) sd += sp[p * 128];
    denom[b * 128 + threadIdx.x] = sd;
  }
}

// ---------- k2: r12 verbatim (r4 math, hi/lo transposed CmT emission)
__global__ __launch_bounds__(256) void k2(const float* __restrict__ ctx,
                                          const float* __restrict__ denom,
                                          const float* __restrict__ w_out,
                                          ushort_t* __restrict__ CmTh,
                                          ushort_t* __restrict__ CmTl) {
  __shared__ float c2s[128][33];
  const int b = blockIdx.x, tid = threadIdx.x;
  for (int i = tid; i < 4096; i += 256) {
    int hd = i >> 5, e = i & 31;
    c2s[hd][e] = SCALE * ctx[b * 4096 + i] / denom[b * 128 + hd];
  }
  __syncthreads();
  for (int o = tid; o < 16384; o += 256) {
    int hd = o >> 7, cc = o & 127, h = hd >> 5;
    float sacc = 0.f;
    #pragma unroll
    for (int e = 0; e < 32; ++e)
      sacc += c2s[hd][e] * w_out[(h * 32 + e) * 128 + cc];
    unsigned int hh = f2bf(sacc);
    CmTh[b * 16384 + cc * 128 + hd] = (ushort_t)hh;
    CmTl[b * 16384 + cc * 128 + hd] = (ushort_t)f2bf(sacc - bf2f((unsigned short)hh));
  }
}

// ---------- k3: r12's k3_hyb with GEMM-1 restructured (acc[32], no reg cache)
__global__ __launch_bounds__(256, 2) void k3_hyb(const float* __restrict__ xg,
                                                 const float* __restrict__ WT,
                                                 const ushort_t* __restrict__ CmTh,
                                                 const ushort_t* __restrict__ CmTl,
                                                 const float* __restrict__ b_out,
                                                 const float* __restrict__ g_ln,
                                                 const float* __restrict__ b_ln,
                                                 float* __restrict__ outg) {
  __shared__ __align__(16) char smem[67840];
  float* Qs = (float*)smem;              // [64*129] fp32 q / qsm / (later) Zs
  float* xs = (float*)(smem + 33024);    // [64*132] fp32 x staging (GEMM-1)
  short* QAh = (short*)(smem + 33024);   // overlay after GEMM-1: [64][136] bf16 q hi
  short* QAl = (short*)(smem + 50432);   // [64][136] bf16 q lo
  const int tid = threadIdx.x;
  const int row0 = blockIdx.x * 64;
  const int b = row0 >> 14;
  float4* xs4 = (float4*)xs;
  const float4* xg4 = (const float4*)xg;
  const float4* WT4 = (const float4*)WT;
  for (int i = tid; i < 2048; i += 256) {
    int row = i >> 5, c4 = i & 31;
    xs4[row * 33 + c4] = xg4[(row0 + row) * 32 + c4];
  }
  __syncthreads();
  const int r = tid & 63, fgrp = tid >> 6;
  {
    // GEMM-1 single-pass: lane = row r, this wave-group owns q cols fb..fb+31.
    // Per-column c4 summation order identical to r12 -> bit-identical results.
    float acc[32];
    #pragma unroll
    for (int u = 0; u < 32; ++u) acc[u] = 0.f;
    const int fb = fgrp * 32;
    for (int c4 = 0; c4 < 32; ++c4) {
      float4 xv = xs4[r * 33 + c4];
      #pragma unroll
      for (int u = 0; u < 32; ++u) {
        float4 wv = WT4[(fb + u) * 32 + c4];   // wave-uniform -> scalar load
        acc[u] += xv.x * wv.x + xv.y * wv.y + xv.z * wv.z + xv.w * wv.w;
      }
    }
    #pragma unroll
    for (int u = 0; u < 32; ++u) Qs[r * 129 + fb + u] = acc[u];
  }
  __syncthreads();
  {   // exact softmax over d per (row, head)
    const int row = tid >> 2, hh = tid & 3;
    const int base = row * 129 + hh * 32;
    float e[32], m = -1e30f;
    #pragma unroll
    for (int j = 0; j < 32; ++j) { e[j] = Qs[base + j]; m = fmaxf(m, e[j]); }
    float s = 0.f;
    #pragma unroll
    for (int j = 0; j < 32; ++j) { e[j] = expf(e[j] - m); s += e[j]; }
    float inv = 1.0f / s;
    #pragma unroll
    for (int j = 0; j < 32; ++j) Qs[base + j] = e[j] * inv;
  }
  __syncthreads();   // xs dead from here; stage qsm -> QAh/QAl (k1kv idiom)
  for (int cid = tid; cid < 1024; cid += 256) {
    int row = cid >> 4, cs = cid & 15;
    float f[8];
    #pragma unroll
    for (int j = 0; j < 8; ++j) f[j] = Qs[row * 129 + cs * 8 + j];
    int4 vh, vl;
    pack_hilo(f, vh, vl);
    *(int4*)&QAh[row * 136 + cs * 8] = vh;
    *(int4*)&QAl[row * 136 + cs * 8] = vl;
  }
  __syncthreads();
  // ---- MFMA GEMM-2: k1kv tiling, staged bf16x8 A-path, B = hi/lo CmT
  const int w = tid >> 6, l = tid & 63;
  const int lr = l & 15, lg = l >> 4;
  const ushort_t* Bh = CmTh + b * 16384;
  const ushort_t* Bl = CmTl + b * 16384;
  f32x4 acc2[4][2];
  #pragma unroll
  for (int i = 0; i < 4; ++i)
    #pragma unroll
    for (int n = 0; n < 2; ++n) acc2[i][n] = (f32x4){0.f, 0.f, 0.f, 0.f};
  #pragma unroll
  for (int kk = 0; kk < 4; ++kk) {
    const int k0 = kk * 32 + lg * 8;
    bf16x8 qh[4], ql[4];
    #pragma unroll
    for (int i = 0; i < 4; ++i) {
      qh[i] = *(const bf16x8*)&QAh[(i * 16 + lr) * 136 + k0];
      ql[i] = *(const bf16x8*)&QAl[(i * 16 + lr) * 136 + k0];
    }
    #pragma unroll
    for (int n = 0; n < 2; ++n) {
      const int cc = w * 32 + n * 16 + lr;
      bf16x8 bh = *(const bf16x8*)(Bh + cc * 128 + k0);
      bf16x8 bl = *(const bf16x8*)(Bl + cc * 128 + k0);
      #pragma unroll
      for (int i = 0; i < 4; ++i) {
        acc2[i][n] = __builtin_amdgcn_mfma_f32_16x16x32_bf16(qh[i], bh, acc2[i][n], 0, 0, 0);
        acc2[i][n] = __builtin_amdgcn_mfma_f32_16x16x32_bf16(qh[i], bl, acc2[i][n], 0, 0, 0);
        acc2[i][n] = __builtin_amdgcn_mfma_f32_16x16x32_bf16(ql[i], bh, acc2[i][n], 0, 0, 0);
      }
    }
  }
  __syncthreads();   // Qs reads done (staging copied it); overlay with Zs
  float* Zs = Qs;
  #pragma unroll
  for (int i = 0; i < 4; ++i)
    #pragma unroll
    for (int n = 0; n < 2; ++n) {
      const int cc = w * 32 + n * 16 + lr;
      #pragma unroll
      for (int rr2 = 0; rr2 < 4; ++rr2) {
        int rr = i * 16 + lg * 4 + rr2;
        Zs[rr * 129 + cc] = acc2[i][n][rr2] + b_out[cc];
      }
    }
  __syncthreads();
  {   // LayerNorm over c, 4 threads/row (r4-verified)
    const int row = tid >> 2, q4 = tid & 3;
    const float* zr = Zs + row * 129 + q4 * 32;
    float vals[32], s = 0.f, ss = 0.f;
    #pragma unroll
    for (int j = 0; j < 32; ++j) {
      float v = zr[j];
      vals[j] = v; s += v; ss += v * v;
    }
    s += __shfl_xor(s, 1);  ss += __shfl_xor(ss, 1);
    s += __shfl_xor(s, 2);  ss += __shfl_xor(ss, 2);
    const float mean = s * (1.f / 128.f);
    const float var  = ss * (1.f / 128.f) - mean * mean;
    const float rstd = rsqrtf(var + 1e-5f);
    float* dst = outg + (row0 + row) * 128 + q4 * 32;
    #pragma unroll
    for (int j = 0; j < 32; ++j)
      dst[j] = (vals[j] - mean) * rstd * g_ln[q4 * 32 + j] + b_ln[q4 * 32 + j];
  }
}

extern "C" void kernel_launch(void* const* d_in, const int* in_sizes, int n_in,
                              void* d_out, int out_size, void* d_ws, size_t ws_size,
                              hipStream_t stream) {
  const float* x     = (const float*)d_in[0];
  const float* w_qkv = (const float*)d_in[1];
  const float* w_out = (const float*)d_in[2];
  const float* b_out = (const float*)d_in[3];
  const float* g_ln  = (const float*)d_in[4];
  const float* b_ln  = (const float*)d_in[5];
  char* ws = (char*)d_ws;
  // ws: ctx @0 (262144); denom @262144 (8192); CmTh @270336 (524288);
  //     CmTl @794624 (524288); WT f32 @1318912 (196608); WTh @1515520 (98304);
  //     WTl @1613824 (98304); pctx @1712128 (33554432); pden @35266560 (1048576)
  float*    ctx   = (float*)ws;
  float*    denom = (float*)(ws + 262144);
  ushort_t* CmTh  = (ushort_t*)(ws + 270336);
  ushort_t* CmTl  = (ushort_t*)(ws + 794624);
  float*    WT    = (float*)(ws + 1318912);
  ushort_t* WTh   = (ushort_t*)(ws + 1515520);
  ushort_t* WTl   = (ushort_t*)(ws + 1613824);
  float*    pctx  = (float*)(ws + 1712128);
  float*    pden  = (float*)(ws + 35266560);
  float* outp = (float*)d_out;

  hipLaunchKernelGGL(kinit, dim3(64),   dim3(256), 0, stream, w_qkv, WT, WTh, WTl);
  hipLaunchKernelGGL(k1kv,  dim3(2048), dim3(256), 0, stream, x, WTh, WTl, pctx, pden);
  hipLaunchKernelGGL(kred,  dim3(256),  dim3(256), 0, stream, pctx, pden, ctx, denom);
  hipLaunchKernelGGL(k2,    dim3(16),   dim3(256), 0, stream, ctx, denom, w_out, CmTh, CmTl);
  hipLaunchKernelGGL(k3_hyb, dim3(4096), dim3(256), 0, stream, x, WT, CmTh, CmTl,
                     b_out, g_ln, b_ln, outp);
}